// Round 4
// baseline (107.746 us; speedup 1.0000x reference)
//
#include <hip/hip_runtime.h>

#define Nn 768
#define Dd 128
#define LDP 136   // padded bf16 row stride (272 B)

typedef __attribute__((ext_vector_type(8))) short bf16x8;
typedef __attribute__((ext_vector_type(4))) float f32x4;
typedef __attribute__((ext_vector_type(4))) int   i32x4;

static __device__ __forceinline__ unsigned short f2bf(float f) {
  unsigned int u = __builtin_bit_cast(unsigned int, f);
  u += 0x7fffu + ((u >> 16) & 1u);   // RNE
  return (unsigned short)(u >> 16);
}
static __device__ __forceinline__ float bf2f(unsigned short h) {
  unsigned int u = ((unsigned int)h) << 16;
  return __builtin_bit_cast(float, u);
}

// left[i][e] = sum_d x[i][d] * W_in[e][d] + b_in[e], stored bf16
__global__ __launch_bounds__(128)
void k_left(const float* __restrict__ x, const float* __restrict__ Win,
            const float* __restrict__ bin, unsigned short* __restrict__ left) {
  __shared__ float sx[Dd];
  const int i = blockIdx.x;
  const int e = threadIdx.x;
  sx[e] = x[i * Dd + e];
  __syncthreads();
  const float4* wrow = (const float4*)(Win + e * Dd);
  float a0 = 0.f, a1 = 0.f, a2 = 0.f, a3 = 0.f;
#pragma unroll
  for (int d4 = 0; d4 < Dd / 4; d4 += 4) {
    float4 w0 = wrow[d4+0], w1 = wrow[d4+1], w2 = wrow[d4+2], w3 = wrow[d4+3];
    a0 += sx[4*d4+ 0]*w0.x + sx[4*d4+ 1]*w0.y + sx[4*d4+ 2]*w0.z + sx[4*d4+ 3]*w0.w;
    a1 += sx[4*d4+ 4]*w1.x + sx[4*d4+ 5]*w1.y + sx[4*d4+ 6]*w1.z + sx[4*d4+ 7]*w1.w;
    a2 += sx[4*d4+ 8]*w2.x + sx[4*d4+ 9]*w2.y + sx[4*d4+10]*w2.z + sx[4*d4+11]*w2.w;
    a3 += sx[4*d4+12]*w3.x + sx[4*d4+13]*w3.y + sx[4*d4+14]*w3.z + sx[4*d4+15]*w3.w;
  }
  left[i * Dd + e] = f2bf(((a0 + a1) + (a2 + a3)) + bin[e]);
}

// One block per i (512 threads, 8 waves). sB = Wout .* left_i staged ONCE,
// then loop over 6 j-tiles: stage sA (32 KB), MFMA C[j][e], direct stores.
// LDS = 2*34816 + 1024 = 70.7 KB -> 2 blocks/CU = 16 waves/CU.
__global__ __launch_bounds__(512, 4)
void k_outer(const unsigned short* __restrict__ left, const float* __restrict__ Wout,
             const float* __restrict__ bout, float* __restrict__ out) {
  __shared__ __attribute__((aligned(16))) unsigned short sB[128 * LDP]; // Wout[e][d]*l_i[d]
  __shared__ __attribute__((aligned(16))) unsigned short sA[128 * LDP]; // left[j-tile][d]
  __shared__ float sLi[Dd];
  __shared__ float sBo[Dd];

  const int i = blockIdx.x;    // 0..767
  const int t = threadIdx.x;   // 0..511

  if (t < Dd) {
    sLi[t] = bf2f(left[i * Dd + t]);
    sBo[t] = bout[t];
  }
  __syncthreads();

  // Stage sB once: 4 threads per row, 32 cols per thread.
  {
    const int r  = t >> 2;          // 0..127
    const int c0 = (t & 3) * 32;
    const float4* wp = (const float4*)(Wout + r * Dd + c0);
#pragma unroll
    for (int q = 0; q < 4; ++q) {
      const int c8 = c0 + q * 8;
      float4 w0 = wp[2*q], w1 = wp[2*q+1];
      unsigned int p0 = (unsigned int)f2bf(w0.x * sLi[c8+0]) | ((unsigned int)f2bf(w0.y * sLi[c8+1]) << 16);
      unsigned int p1 = (unsigned int)f2bf(w0.z * sLi[c8+2]) | ((unsigned int)f2bf(w0.w * sLi[c8+3]) << 16);
      unsigned int p2 = (unsigned int)f2bf(w1.x * sLi[c8+4]) | ((unsigned int)f2bf(w1.y * sLi[c8+5]) << 16);
      unsigned int p3 = (unsigned int)f2bf(w1.z * sLi[c8+6]) | ((unsigned int)f2bf(w1.w * sLi[c8+7]) << 16);
      i32x4 vb; vb[0] = (int)p0; vb[1] = (int)p1; vb[2] = (int)p2; vb[3] = (int)p3;
      *(i32x4*)(sB + r * LDP + c8) = vb;
    }
  }

  const int wid  = t >> 6;         // 0..7 -> j rows [wid*16, wid*16+16)
  const int lane = t & 63;
  const int l15  = lane & 15;
  const int kq   = (lane >> 4) * 8;

  for (int jt = 0; jt < 6; ++jt) {
    __syncthreads();   // prior readers of sA done (and, first iter, sB staged)

    // Stage sA: 2048 x 16B chunks over 512 threads (4 each), coalesced.
#pragma unroll
    for (int it = 0; it < 4; ++it) {
      const int idx = t + it * 512;
      const int r   = idx >> 4;
      const int c8  = (idx & 15) * 8;
      *(i32x4*)(sA + r * LDP + c8) = *(const i32x4*)(left + (jt * 128 + r) * Dd + c8);
    }
    __syncthreads();

    f32x4 acc[8] = {};   // n over e-chunks; C[j][e]
#pragma unroll
    for (int kb = 0; kb < 4; ++kb) {
      const int k = kb * 32 + kq;
      bf16x8 a = *(const bf16x8*)(sA + (wid * 16 + l15) * LDP + k);
#pragma unroll
      for (int n = 0; n < 8; ++n) {
        bf16x8 b = *(const bf16x8*)(sB + (n * 16 + l15) * LDP + k);
        acc[n] = __builtin_amdgcn_mfma_f32_16x16x32_bf16(a, b, acc[n], 0, 0, 0);
      }
    }

    // Stores: row(j) = (lane>>4)*4 + r, col(e) = n*16 + l15.
    const int jbase = jt * 128 + wid * 16 + (lane >> 4) * 4;
    float* obase = out + ((size_t)i * Nn + jbase) * Dd;
#pragma unroll
    for (int n = 0; n < 8; ++n) {
      const int e = n * 16 + l15;
      const float bias = sBo[e];
#pragma unroll
      for (int r = 0; r < 4; ++r) {
        __builtin_nontemporal_store(acc[n][r] + bias, obase + (size_t)r * Dd + e);
      }
    }
  }
}

extern "C" void kernel_launch(void* const* d_in, const int* in_sizes, int n_in,
                              void* d_out, int out_size, void* d_ws, size_t ws_size,
                              hipStream_t stream) {
  const float* x    = (const float*)d_in[0];
  const float* Win  = (const float*)d_in[1];
  const float* bin  = (const float*)d_in[2];
  const float* Wout = (const float*)d_in[3];
  const float* bout = (const float*)d_in[4];
  float* out = (float*)d_out;
  unsigned short* left = (unsigned short*)d_ws;  // 768*128 bf16 = 192 KiB

  k_left<<<Nn, Dd, 0, stream>>>(x, Win, bin, left);
  k_outer<<<Nn, 512, 0, stream>>>(left, Wout, bout, out);
}